// Round 3
// baseline (1060.031 us; speedup 1.0000x reference)
//
#include <hip/hip_runtime.h>

#define T_STEPS 2048
#define BATCH   128
#define HID     100     // LSTM hidden size
#define HP      112     // padded hidden length (multiple of 16)
#define NTH     448     // 7 waves of 64

#define LOG2E 1.44269504088896340736f

typedef float v2f __attribute__((ext_vector_type(2)));

// DPP quad_perm helpers (VALU pipe, immediate ctrl)
template <int CTRL>
__device__ __forceinline__ float dpp_mov(float v) {
    int y = __builtin_amdgcn_update_dpp(0, __float_as_int(v), CTRL, 0xF, 0xF, true);
    return __int_as_float(y);
}

// packed f32 fma -> v_pk_fma_f32 (VOP3P, 2 FMAs/instr; the only path to the
// 157 TF f32 vector peak on gfx950)
static __device__ __forceinline__ v2f pk_fma(v2f a, v2f b, v2f c) {
#if __has_builtin(__builtin_elementwise_fma)
    return __builtin_elementwise_fma(a, b, c);
#else
    v2f r; r.x = fmaf(a.x, b.x, c.x); r.y = fmaf(a.y, b.y, c.y); return r;
#endif
}

__global__ __launch_bounds__(NTH)
__attribute__((amdgpu_waves_per_eu(1)))   // min-only: full unified VGPR budget
void lstm_caviar_kernel(
    const float* __restrict__ x,      // [T, B, 1]
    const float* __restrict__ W_ih,   // [400, 1]
    const float* __restrict__ W_hh,   // [400, 100]
    const float* __restrict__ b_ih,   // [400]
    const float* __restrict__ b_hh,   // [400]
    const float* __restrict__ W1,     // [64, 100]
    const float* __restrict__ b1,     // [64]
    const float* __restrict__ W2,     // [1, 64]
    const float* __restrict__ b2,     // [1]
    float* __restrict__ out)          // [1]
{
    __shared__ __align__(16) float h_buf[2][HP];
    __shared__ float x_lds[T_STEPS];
    __shared__ float red_lds[64];

    const int tid = threadIdx.x;
    const int j   = tid >> 2;     // hidden unit owned by this quad
    const int s   = tid & 3;      // k-split / gate-specialization lane
    const bool active = (j < HID);

    // stage batch-0 inputs (x[t,0,0] = flat[t*BATCH]) into LDS once
    for (int t = tid; t < T_STEPS; t += NTH)
        x_lds[t] = x[t * BATCH];
    if (tid < HP) { h_buf[0][tid] = 0.0f; h_buf[1][tid] = 0.0f; }

    // Preload W_hh fragments as float2 PAIRS for v_pk_fma_f32.
    // Lane covers k = 16*m + 4*s + d, m=0..6, d=0..3  ->  pairs (d=0,1),(d=2,3).
    // wi/bias pre-scaled by 0.25 so the 4-lane reduce sums them to exactly 1x.
    // All gate rows pre-scaled by log2(e) (2*log2(e) for gate g) so activations
    // use v_exp_f32 (exp2) directly:
    //   sigmoid(p) = rcp(1 + exp2(-L*p)),  tanh(p) = 2*rcp(1 + exp2(-2L*p)) - 1
    v2f w2[4][14];
    float wi4[4], bs4[4];
    #pragma unroll
    for (int g = 0; g < 4; ++g) {
        const int gate = g * HID + (active ? j : 0);
        const float Lg = (g == 2) ? (2.0f * LOG2E) : LOG2E;
        const float* row = W_hh + gate * HID;
        #pragma unroll
        for (int m = 0; m < 7; ++m) {
            #pragma unroll
            for (int p = 0; p < 2; ++p) {
                const int k0 = 16 * m + 4 * s + 2 * p;
                v2f wp;
                wp.x = (active && k0     < HID) ? Lg * row[k0]     : 0.0f;
                wp.y = (active && k0 + 1 < HID) ? Lg * row[k0 + 1] : 0.0f;
                w2[g][2 * m + p] = wp;
            }
        }
        wi4[g] = active ? 0.25f * Lg * W_ih[gate] : 0.0f;
        bs4[g] = active ? 0.25f * Lg * (b_ih[gate] + b_hh[gate]) : 0.0f;
    }

    const bool b0   = (s & 1) != 0;
    const bool b1h  = (s & 2) != 0;
    const bool is_g = (s == 2);
    const bool wr   = active && (s == 0);
    const int  hoff = 4 * s;      // this lane's float4 slot within a 16-chunk
    float c = 0.0f;
    __syncthreads();

    // one LSTM step: read h from hb, write new h to hout (static buffers via
    // 2x unroll -> LDS base regs are loop-invariant, offsets are immediates)
    auto step = [&](const float* hb, const float xt, float* hout) {
        // bias/input contribution folded into acc.x
        v2f acc0 = {fmaf(wi4[0], xt, bs4[0]), 0.0f};
        v2f acc1 = {fmaf(wi4[1], xt, bs4[1]), 0.0f};
        v2f acc2 = {fmaf(wi4[2], xt, bs4[2]), 0.0f};
        v2f acc3 = {fmaf(wi4[3], xt, bs4[3]), 0.0f};

        const float* hbase = hb + hoff;
        #pragma unroll
        for (int m = 0; m < 7; ++m) {
            const float4 hv = *(const float4*)(hbase + 16 * m);
            const v2f hlo = {hv.x, hv.y};
            const v2f hhi = {hv.z, hv.w};
            acc0 = pk_fma(w2[0][2*m],   hlo, acc0);
            acc0 = pk_fma(w2[0][2*m+1], hhi, acc0);
            acc1 = pk_fma(w2[1][2*m],   hlo, acc1);
            acc1 = pk_fma(w2[1][2*m+1], hhi, acc1);
            acc2 = pk_fma(w2[2][2*m],   hlo, acc2);
            acc2 = pk_fma(w2[2][2*m+1], hhi, acc2);
            acc3 = pk_fma(w2[3][2*m],   hlo, acc3);
            acc3 = pk_fma(w2[3][2*m+1], hhi, acc3);
        }

        const float a0 = acc0.x + acc0.y;
        const float a1 = acc1.x + acc1.y;
        const float a2 = acc2.x + acc2.y;
        const float a3 = acc3.x + acc3.y;

        // Select-then-butterfly transpose-reduce: lane s ends with the FULL
        // sum of gate s (12 VALU ops).
        float p01  = b0 ? a1 : a0;
        float p01s = b0 ? a0 : a1;
        float p23  = b0 ? a3 : a2;
        float p23s = b0 ? a2 : a3;
        p01 += dpp_mov<0xB1>(p01s);
        p23 += dpp_mov<0xB1>(p23s);
        float q  = b1h ? p23 : p01;
        float qs = b1h ? p01 : p23;
        const float tot = q + dpp_mov<0x4E>(qs);

        // lane s activates gate s (i,f,o: sigmoid; g: tanh) — log2e baked in
        const float e   = __builtin_amdgcn_exp2f(-tot);
        const float r   = __builtin_amdgcn_rcpf(1.0f + e);
        const float act = is_g ? fmaf(2.0f, r, -1.0f) : r;

        // redistribute the four activations within the quad (DPP broadcasts)
        const float ig = dpp_mov<0x00>(act);
        const float fg = dpp_mov<0x55>(act);
        const float gg = dpp_mov<0xAA>(act);
        const float og = dpp_mov<0xFF>(act);

        c = fmaf(fg, c, ig * gg);
        const float e2 = __builtin_amdgcn_exp2f(-2.0f * LOG2E * c);
        const float r2 = __builtin_amdgcn_rcpf(1.0f + e2);
        const float h  = og * fmaf(2.0f, r2, -1.0f);

        if (wr) hout[j] = h;
        __syncthreads();
    };

    for (int t = 0; t < T_STEPS; t += 2) {
        step(h_buf[0], x_lds[t],     h_buf[1]);
        step(h_buf[1], x_lds[t + 1], h_buf[0]);
    }

    // head: lin = W1 @ h + b1 (64), out = W2 @ lin + b2 (scalar)
    if (tid < 64) {
        const float* rw = W1 + tid * HID;
        const float* hf = h_buf[0];   // T even -> final h in buf 0
        float a = 0.0f;
        for (int k = 0; k < HID; ++k)
            a = fmaf(rw[k], hf[k], a);
        red_lds[tid] = a + b1[tid];
    }
    __syncthreads();
    if (tid == 0) {
        float a = b2[0];
        for (int k = 0; k < 64; ++k)
            a = fmaf(W2[k], red_lds[k], a);
        out[0] = a;
    }
}

extern "C" void kernel_launch(void* const* d_in, const int* in_sizes, int n_in,
                              void* d_out, int out_size, void* d_ws, size_t ws_size,
                              hipStream_t stream) {
    lstm_caviar_kernel<<<1, NTH, 0, stream>>>(
        (const float*)d_in[0],  // input_seq
        (const float*)d_in[1],  // W_ih
        (const float*)d_in[2],  // W_hh
        (const float*)d_in[3],  // b_ih
        (const float*)d_in[4],  // b_hh
        (const float*)d_in[5],  // W1
        (const float*)d_in[6],  // b1
        (const float*)d_in[7],  // W2
        (const float*)d_in[8],  // b2
        (float*)d_out);
}

// Round 4
// 1012.159 us; speedup vs baseline: 1.0473x; 1.0473x over previous
//
#include <hip/hip_runtime.h>

#define T_STEPS 2048
#define BATCH   128
#define HID     100     // LSTM hidden size
#define HP      112     // padded hidden length (multiple of 16)
#define NTH     448     // 7 waves of 64

#define LOG2E 1.44269504088896340736f

// DPP quad_perm helpers (VALU pipe, immediate ctrl)
template <int CTRL>
__device__ __forceinline__ float dpp_mov(float v) {
    int y = __builtin_amdgcn_update_dpp(0, __float_as_int(v), CTRL, 0xF, 0xF, true);
    return __int_as_float(y);
}

__global__ __launch_bounds__(NTH)
__attribute__((amdgpu_waves_per_eu(1, 2)))
// min=1, MAX=2 waves/EU: a 448-thread wg needs exactly 2 waves/SIMD resident
// (2,2,2,1). Declaring the max tells regalloc occupancy can't exceed that, so
// there is no value in saving registers -> the ~120 loop-carried weight floats
// should be homed in ARCH VGPRs (2 x ~230 <= 512 regs/SIMD), killing the
// per-use v_accvgpr_read traffic that dominates VALU issue (R1/R3 counters).
void lstm_caviar_kernel(
    const float* __restrict__ x,      // [T, B, 1]
    const float* __restrict__ W_ih,   // [400, 1]
    const float* __restrict__ W_hh,   // [400, 100]
    const float* __restrict__ b_ih,   // [400]
    const float* __restrict__ b_hh,   // [400]
    const float* __restrict__ W1,     // [64, 100]
    const float* __restrict__ b1,     // [64]
    const float* __restrict__ W2,     // [1, 64]
    const float* __restrict__ b2,     // [1]
    float* __restrict__ out)          // [1]
{
    __shared__ __align__(16) float h_buf[2][HP];
    __shared__ float x_lds[T_STEPS];
    __shared__ float red_lds[64];

    const int tid = threadIdx.x;
    const int j   = tid >> 2;     // hidden unit owned by this quad
    const int s   = tid & 3;      // k-split / gate-specialization lane
    const bool active = (j < HID);

    // stage batch-0 inputs (x[t,0,0] = flat[t*BATCH]) into LDS once
    for (int t = tid; t < T_STEPS; t += NTH)
        x_lds[t] = x[t * BATCH];
    if (tid < HP) { h_buf[0][tid] = 0.0f; h_buf[1][tid] = 0.0f; }

    // Preload W_hh fragments: lane covers k = 16*m + 4*s + d, m=0..6, d=0..3.
    // wi/bias pre-scaled by 0.25 so the 4-lane reduce sums them to exactly 1x.
    // All gate rows pre-scaled by log2(e) (2*log2(e) for gate g) so activations
    // use v_exp_f32 (exp2) directly:
    //   sigmoid(p) = rcp(1 + exp2(-L*p)),  tanh(p) = 2*rcp(1 + exp2(-2L*p)) - 1
    float w[4][28];
    float wi4[4], bs4[4];
    #pragma unroll
    for (int g = 0; g < 4; ++g) {
        const int gate = g * HID + (active ? j : 0);
        const float Lg = (g == 2) ? (2.0f * LOG2E) : LOG2E;
        const float* row = W_hh + gate * HID;
        #pragma unroll
        for (int m = 0; m < 7; ++m) {
            #pragma unroll
            for (int d = 0; d < 4; ++d) {
                const int k = 16 * m + 4 * s + d;
                w[g][m * 4 + d] = (active && k < HID) ? Lg * row[k] : 0.0f;
            }
        }
        wi4[g] = active ? 0.25f * Lg * W_ih[gate] : 0.0f;
        bs4[g] = active ? 0.25f * Lg * (b_ih[gate] + b_hh[gate]) : 0.0f;
    }

    const bool b0   = (s & 1) != 0;
    const bool b1h  = (s & 2) != 0;
    const bool is_g = (s == 2);
    float c = 0.0f;
    __syncthreads();

    for (int t = 0; t < T_STEPS; ++t) {
        const float* hb = h_buf[t & 1];
        const float xt = x_lds[t];

        float acc0 = fmaf(wi4[0], xt, bs4[0]);
        float acc1 = fmaf(wi4[1], xt, bs4[1]);
        float acc2 = fmaf(wi4[2], xt, bs4[2]);
        float acc3 = fmaf(wi4[3], xt, bs4[3]);

        #pragma unroll
        for (int m = 0; m < 7; ++m) {
            const float4 hv = *(const float4*)(hb + 16 * m + 4 * s);
            acc0 = fmaf(w[0][m*4+0], hv.x, acc0);
            acc0 = fmaf(w[0][m*4+1], hv.y, acc0);
            acc0 = fmaf(w[0][m*4+2], hv.z, acc0);
            acc0 = fmaf(w[0][m*4+3], hv.w, acc0);
            acc1 = fmaf(w[1][m*4+0], hv.x, acc1);
            acc1 = fmaf(w[1][m*4+1], hv.y, acc1);
            acc1 = fmaf(w[1][m*4+2], hv.z, acc1);
            acc1 = fmaf(w[1][m*4+3], hv.w, acc1);
            acc2 = fmaf(w[2][m*4+0], hv.x, acc2);
            acc2 = fmaf(w[2][m*4+1], hv.y, acc2);
            acc2 = fmaf(w[2][m*4+2], hv.z, acc2);
            acc2 = fmaf(w[2][m*4+3], hv.w, acc2);
            acc3 = fmaf(w[3][m*4+0], hv.x, acc3);
            acc3 = fmaf(w[3][m*4+1], hv.y, acc3);
            acc3 = fmaf(w[3][m*4+2], hv.z, acc3);
            acc3 = fmaf(w[3][m*4+3], hv.w, acc3);
        }

        // Select-then-butterfly transpose-reduce: lane s ends with the FULL
        // sum of gate s (12 VALU ops).
        float p01  = b0 ? acc1 : acc0;
        float p01s = b0 ? acc0 : acc1;
        float p23  = b0 ? acc3 : acc2;
        float p23s = b0 ? acc2 : acc3;
        p01 += dpp_mov<0xB1>(p01s);
        p23 += dpp_mov<0xB1>(p23s);
        float q  = b1h ? p23 : p01;
        float qs = b1h ? p01 : p23;
        const float tot = q + dpp_mov<0x4E>(qs);

        // lane s activates gate s (i,f,o: sigmoid; g: tanh) — log2e baked in
        const float e   = __builtin_amdgcn_exp2f(-tot);
        const float r   = __builtin_amdgcn_rcpf(1.0f + e);
        const float act = is_g ? fmaf(2.0f, r, -1.0f) : r;

        // redistribute the four activations within the quad (DPP broadcasts)
        const float ig = dpp_mov<0x00>(act);
        const float fg = dpp_mov<0x55>(act);
        const float gg = dpp_mov<0xAA>(act);
        const float og = dpp_mov<0xFF>(act);

        c = fmaf(fg, c, ig * gg);
        const float e2 = __builtin_amdgcn_exp2f(-2.0f * LOG2E * c);
        const float r2 = __builtin_amdgcn_rcpf(1.0f + e2);
        const float h  = og * fmaf(2.0f, r2, -1.0f);

        if (active && s == 0)
            h_buf[(t + 1) & 1][j] = h;
        __syncthreads();
    }

    // head: lin = W1 @ h + b1 (64), out = W2 @ lin + b2 (scalar)
    if (tid < 64) {
        const float* rw = W1 + tid * HID;
        const float* hf = h_buf[0];   // T even -> final h in buf 0
        float a = 0.0f;
        for (int k = 0; k < HID; ++k)
            a = fmaf(rw[k], hf[k], a);
        red_lds[tid] = a + b1[tid];
    }
    __syncthreads();
    if (tid == 0) {
        float a = b2[0];
        for (int k = 0; k < 64; ++k)
            a = fmaf(W2[k], red_lds[k], a);
        out[0] = a;
    }
}

extern "C" void kernel_launch(void* const* d_in, const int* in_sizes, int n_in,
                              void* d_out, int out_size, void* d_ws, size_t ws_size,
                              hipStream_t stream) {
    lstm_caviar_kernel<<<1, NTH, 0, stream>>>(
        (const float*)d_in[0],  // input_seq
        (const float*)d_in[1],  // W_ih
        (const float*)d_in[2],  // W_hh
        (const float*)d_in[3],  // b_ih
        (const float*)d_in[4],  // b_hh
        (const float*)d_in[5],  // W1
        (const float*)d_in[6],  // b1
        (const float*)d_in[7],  // W2
        (const float*)d_in[8],  // b2
        (float*)d_out);
}